// Round 1
// baseline (10430.057 us; speedup 1.0000x reference)
//
#include <hip/hip_runtime.h>
#include <stdint.h>

#define T_LEN 4096
#define E_DIM 256
#define HH 256

typedef unsigned long long u64;

__device__ __forceinline__ float sigmoidf_(float x) { return 1.0f / (1.0f + __expf(-x)); }

// ---------------------------------------------------------------------------
// Kernel 1: embedding gather fused with input projection.
// gates_d[t][r] = dot(Wih_d[r,:], embed[sent[t],:]) + bih_d[r] + bhh_d[r]
// Block = 256 threads handles 16 timesteps x all 1024 rows of one direction.
// ---------------------------------------------------------------------------
__global__ __launch_bounds__(256) void proj_kernel(
    const int* __restrict__ sent, const float* __restrict__ embed,
    const float* __restrict__ Wih_f, const float* __restrict__ bih_f, const float* __restrict__ bhh_f,
    const float* __restrict__ Wih_b, const float* __restrict__ bih_b, const float* __restrict__ bhh_b,
    float* __restrict__ gates_f, float* __restrict__ gates_b)
{
    __shared__ float4 xt[16][64];   // 16 timesteps x 256 floats
    const int tid = threadIdx.x;
    const int dir = blockIdx.y;
    const int t0  = blockIdx.x * 16;

    const float* Wih = dir ? Wih_b : Wih_f;
    const float* bih = dir ? bih_b : bih_f;
    const float* bhh = dir ? bhh_b : bhh_f;
    float* gates     = dir ? gates_b : gates_f;

    {   // gather 16 embedding rows into LDS (coalesced 16B/lane)
        int row = tid >> 4;         // 0..15
        int c   = tid & 15;         // 0..15
        const float4* src = (const float4*)(embed + (size_t)sent[t0 + row] * E_DIM);
        xt[row][c]      = src[c];
        xt[row][c + 16] = src[c + 16];
        xt[row][c + 32] = src[c + 32];
        xt[row][c + 48] = src[c + 48];
    }
    __syncthreads();

    float acc[4][16];
    #pragma unroll
    for (int ri = 0; ri < 4; ++ri)
        #pragma unroll
        for (int tt = 0; tt < 16; ++tt) acc[ri][tt] = 0.f;

    const float4* wrow0 = (const float4*)(Wih + (size_t)(0 * 256 + tid) * 256);
    const float4* wrow1 = (const float4*)(Wih + (size_t)(1 * 256 + tid) * 256);
    const float4* wrow2 = (const float4*)(Wih + (size_t)(2 * 256 + tid) * 256);
    const float4* wrow3 = (const float4*)(Wih + (size_t)(3 * 256 + tid) * 256);

    for (int k4 = 0; k4 < 64; ++k4) {
        float4 xv[16];
        #pragma unroll
        for (int tt = 0; tt < 16; ++tt) xv[tt] = xt[tt][k4];  // LDS broadcast
        float4 w0 = wrow0[k4], w1 = wrow1[k4], w2 = wrow2[k4], w3 = wrow3[k4];
        #pragma unroll
        for (int tt = 0; tt < 16; ++tt) {
            acc[0][tt] += w0.x*xv[tt].x + w0.y*xv[tt].y + w0.z*xv[tt].z + w0.w*xv[tt].w;
            acc[1][tt] += w1.x*xv[tt].x + w1.y*xv[tt].y + w1.z*xv[tt].z + w1.w*xv[tt].w;
            acc[2][tt] += w2.x*xv[tt].x + w2.y*xv[tt].y + w2.z*xv[tt].z + w2.w*xv[tt].w;
            acc[3][tt] += w3.x*xv[tt].x + w3.y*xv[tt].y + w3.z*xv[tt].z + w3.w*xv[tt].w;
        }
    }

    #pragma unroll
    for (int ri = 0; ri < 4; ++ri) {
        int r = ri * 256 + tid;
        float b = bih[r] + bhh[r];
        #pragma unroll
        for (int tt = 0; tt < 16; ++tt)
            gates[(size_t)(t0 + tt) * 1024 + r] = acc[ri][tt] + b;
    }
}

// ---------------------------------------------------------------------------
// Kernel 2: the bidirectional LSTM recurrence.
// 8 blocks: blocks 0-3 forward, 4-7 backward. Each block owns 64 hidden units
// (=> 256 gate rows of Whh, kept register-resident: 128 floats/thread).
// Cross-block h broadcast: 64-bit (tag|value) relaxed agent-scope atomics,
// double-buffered by step parity. Tag carries readiness -> no fences needed.
// ---------------------------------------------------------------------------
__global__ __launch_bounds__(512, 2) void lstm_kernel(
    const float* __restrict__ Whh_f, const float* __restrict__ Whh_b,
    const float* __restrict__ gates_f, const float* __restrict__ gates_b,
    const float* __restrict__ h0, const float* __restrict__ c0,
    float* __restrict__ h_out, u64* __restrict__ msg)
{
    const int tid  = threadIdx.x;
    const int dir  = blockIdx.x >> 2;
    const int g    = blockIdx.x & 3;
    const int rl   = tid & 255;       // row-local 0..255
    const int half = tid >> 8;        // k-half 0/1
    const int gate = rl >> 6;         // 0..3 (i,f,g,o)
    const int jj   = rl & 63;
    const int j    = g * 64 + jj;     // hidden index within direction
    const int r    = gate * 256 + j;  // global gate row 0..1023

    const float* Whh   = dir ? Whh_b : Whh_f;
    const float* gates = dir ? gates_b : gates_f;

    // register-resident weight half-row (128 floats = 32 float4)
    float4 wv[32];
    {
        const float4* wp = (const float4*)(Whh + (size_t)r * 256 + half * 128);
        #pragma unroll
        for (int i = 0; i < 32; ++i) wv[i] = wp[i];
    }

    __shared__ float h_lds[256];
    __shared__ float part[512];
    __shared__ float gval[256];

    float c = 0.f;
    if (tid < 64) {
        c = c0[dir * HH + j];
        float h = h0[dir * HH + j];
        u64 p = ((u64)1u << 32) | (u64)__float_as_uint(h);
        __hip_atomic_store(&msg[(0 * 2 + dir) * 256 + j], p,
                           __ATOMIC_RELAXED, __HIP_MEMORY_SCOPE_AGENT);
    }

    for (int t = 0; t < T_LEN; ++t) {
        const int tf = dir ? (T_LEN - 1 - t) : t;

        // prefetch gate input (overlaps the spin)
        float gin = 0.f;
        if (tid < 256) gin = gates[(size_t)tf * 1024 + r];

        // wait for full h_prev with tag t+1
        if (tid < 256) {
            u64* slot = &msg[((t & 1) * 2 + dir) * 256 + tid];
            const unsigned want = (unsigned)(t + 1);
            u64 m;
            do {
                m = __hip_atomic_load(slot, __ATOMIC_RELAXED, __HIP_MEMORY_SCOPE_AGENT);
            } while ((unsigned)(m >> 32) != want);
            h_lds[tid] = __uint_as_float((unsigned)m);
        }
        __syncthreads();

        // half-row dot product
        float p = 0.f;
        const float4* hp = (const float4*)(h_lds + half * 128);
        #pragma unroll
        for (int i = 0; i < 32; ++i) {
            float4 h4 = hp[i];
            p += wv[i].x*h4.x + wv[i].y*h4.y + wv[i].z*h4.z + wv[i].w*h4.w;
        }
        part[tid] = p;
        __syncthreads();

        if (tid < 256) gval[tid] = part[tid] + part[tid + 256] + gin;
        __syncthreads();

        if (tid < 64) {
            float iv = sigmoidf_(gval[jj]);
            float fv = sigmoidf_(gval[64 + jj]);
            float gv = tanhf(gval[128 + jj]);
            float ov = sigmoidf_(gval[192 + jj]);
            c = fv * c + iv * gv;
            float h = ov * tanhf(c);
            h_out[(size_t)tf * 512 + dir * HH + j] = h;
            u64 pck = ((u64)(unsigned)(t + 2) << 32) | (u64)__float_as_uint(h);
            __hip_atomic_store(&msg[(((t + 1) & 1) * 2 + dir) * 256 + j], pck,
                               __ATOMIC_RELAXED, __HIP_MEMORY_SCOPE_AGENT);
        }
        // no extra barrier needed: next poll only rewrites h_lds, which was
        // last read before the part[] barrier; gval writes sit behind two
        // barriers of the next iteration.
    }
}

// ---------------------------------------------------------------------------
// Kernel 3: feats[t][k] = dot(h_out[t,:], W_out[k,:]) + b_out[k]
// One wave per timestep; lane pair per output tag.
// ---------------------------------------------------------------------------
__global__ __launch_bounds__(64) void feats_kernel(
    const float* __restrict__ h_out, const float* __restrict__ W_out,
    const float* __restrict__ b_out, float* __restrict__ feats)
{
    const int t = blockIdx.x;
    const int lane = threadIdx.x;
    const int k = lane >> 1, half = lane & 1;
    const float4* hv = (const float4*)(h_out + (size_t)t * 512 + half * 256);
    const float4* wv = (const float4*)(W_out + (size_t)k * 512 + half * 256);
    float p = 0.f;
    #pragma unroll 16
    for (int i = 0; i < 64; ++i) {
        float4 a = hv[i], b = wv[i];
        p += a.x*b.x + a.y*b.y + a.z*b.z + a.w*b.w;
    }
    p += __shfl_xor(p, 1);
    if (half == 0) feats[t * 32 + k] = p + b_out[k];
}

// ---------------------------------------------------------------------------
// Kernel 4: Viterbi. Single wave: lane = 2*j + i_half. Backpointers in
// dynamic LDS (128 KB) so the serial backtrace stays at LDS latency.
// Candidate = (alpha[i] + trans[i][j]) + obs[j], matching the reference's
// association order so argmax ties track numpy.
// ---------------------------------------------------------------------------
__global__ __launch_bounds__(64) void viterbi_kernel(
    const float* __restrict__ feats, const float* __restrict__ trans,
    float* __restrict__ out)
{
    extern __shared__ unsigned char ixs[];   // (T-1) * 32 backpointers
    __shared__ float fin[32];

    const int lane = threadIdx.x;
    const int j = lane >> 1, ih = lane & 1;

    float ttr[16];
    #pragma unroll
    for (int q = 0; q < 16; ++q) ttr[q] = trans[(ih * 16 + q) * 32 + j];

    float alpha = feats[j];

    for (int t = 1; t < T_LEN; ++t) {
        float obs = feats[t * 32 + j];
        float best = -3.4e38f; int barg = 0;
        #pragma unroll
        for (int q = 0; q < 16; ++q) {
            int i = ih * 16 + q;
            float cand = (__shfl(alpha, 2 * i) + ttr[q]) + obs;
            if (cand > best) { best = cand; barg = i; }
        }
        // merge the two i-halves; prefer lower i on exact ties
        float ob = __shfl_xor(best, 1); int oa = __shfl_xor(barg, 1);
        float m0 = ih ? ob : best; int a0 = ih ? oa : barg;
        float m1 = ih ? best : ob; int a1 = ih ? barg : oa;
        float m = m0; int a = a0;
        if (m1 > m0) { m = m1; a = a1; }
        if (ih == 0) ixs[(t - 1) * 32 + j] = (unsigned char)a;
        alpha = m;
    }

    if (ih == 0) fin[j] = alpha;
    __syncthreads();

    if (lane == 0) {
        float sc = fin[0]; int cur = 0;
        for (int q = 1; q < 32; ++q)
            if (fin[q] > sc) { sc = fin[q]; cur = q; }
        out[T_LEN] = sc;                 // score after the T path entries
        out[T_LEN - 1] = (float)cur;
        for (int t = T_LEN - 2; t >= 0; --t) {
            cur = ixs[t * 32 + cur];
            out[t] = (float)cur;
        }
    }
}

// ---------------------------------------------------------------------------
extern "C" void kernel_launch(void* const* d_in, const int* in_sizes, int n_in,
                              void* d_out, int out_size, void* d_ws, size_t ws_size,
                              hipStream_t stream) {
    const int*   sent  = (const int*)d_in[0];
    const float* embed = (const float*)d_in[1];
    const float* Wih_f = (const float*)d_in[2];
    const float* Whh_f = (const float*)d_in[3];
    const float* bih_f = (const float*)d_in[4];
    const float* bhh_f = (const float*)d_in[5];
    const float* Wih_b = (const float*)d_in[6];
    const float* Whh_b = (const float*)d_in[7];
    const float* bih_b = (const float*)d_in[8];
    const float* bhh_b = (const float*)d_in[9];
    const float* h0    = (const float*)d_in[10];
    const float* c0    = (const float*)d_in[11];
    const float* W_out = (const float*)d_in[12];
    const float* b_out = (const float*)d_in[13];
    const float* trans = (const float*)d_in[14];
    float* out = (float*)d_out;

    float* gates_f = (float*)d_ws;                              // T*1024
    float* gates_b = gates_f + (size_t)T_LEN * 1024;            // T*1024
    float* h_out   = gates_b + (size_t)T_LEN * 1024;            // T*512
    float* feats   = h_out   + (size_t)T_LEN * 512;             // T*32
    u64*   msg     = (u64*)(feats + (size_t)T_LEN * 32);        // 2*2*256

    dim3 gproj(T_LEN / 16, 2);
    proj_kernel<<<gproj, 256, 0, stream>>>(sent, embed,
        Wih_f, bih_f, bhh_f, Wih_b, bih_b, bhh_b, gates_f, gates_b);

    lstm_kernel<<<8, 512, 0, stream>>>(Whh_f, Whh_b, gates_f, gates_b,
                                       h0, c0, h_out, msg);

    feats_kernel<<<T_LEN, 64, 0, stream>>>(h_out, W_out, b_out, feats);

    hipFuncSetAttribute((const void*)viterbi_kernel,
                        hipFuncAttributeMaxDynamicSharedMemorySize, 132 * 1024);
    viterbi_kernel<<<1, 64, (T_LEN - 1) * 32, stream>>>(feats, trans, out);
}

// Round 3
// 9865.271 us; speedup vs baseline: 1.0572x; 1.0572x over previous
//
#include <hip/hip_runtime.h>
#include <stdint.h>

#define T_LEN 4096
#define E_DIM 256
#define HH 256

typedef unsigned long long u64;

__device__ __forceinline__ float sigmoidf_(float x) { return 1.0f / (1.0f + __expf(-x)); }

// ---------------------------------------------------------------------------
// Kernel 1: embedding gather fused with input projection.
// gates_d[t][r] = dot(Wih_d[r,:], embed[sent[t],:]) + bih_d[r] + bhh_d[r]
// ---------------------------------------------------------------------------
__global__ __launch_bounds__(256) void proj_kernel(
    const int* __restrict__ sent, const float* __restrict__ embed,
    const float* __restrict__ Wih_f, const float* __restrict__ bih_f, const float* __restrict__ bhh_f,
    const float* __restrict__ Wih_b, const float* __restrict__ bih_b, const float* __restrict__ bhh_b,
    float* __restrict__ gates_f, float* __restrict__ gates_b)
{
    __shared__ float4 xt[16][64];   // 16 timesteps x 256 floats
    const int tid = threadIdx.x;
    const int dir = blockIdx.y;
    const int t0  = blockIdx.x * 16;

    const float* Wih = dir ? Wih_b : Wih_f;
    const float* bih = dir ? bih_b : bih_f;
    const float* bhh = dir ? bhh_b : bhh_f;
    float* gates     = dir ? gates_b : gates_f;

    {   // gather 16 embedding rows into LDS (coalesced 16B/lane)
        int row = tid >> 4;
        int c   = tid & 15;
        const float4* src = (const float4*)(embed + (size_t)sent[t0 + row] * E_DIM);
        xt[row][c]      = src[c];
        xt[row][c + 16] = src[c + 16];
        xt[row][c + 32] = src[c + 32];
        xt[row][c + 48] = src[c + 48];
    }
    __syncthreads();

    float acc[4][16];
    #pragma unroll
    for (int ri = 0; ri < 4; ++ri)
        #pragma unroll
        for (int tt = 0; tt < 16; ++tt) acc[ri][tt] = 0.f;

    const float4* wrow0 = (const float4*)(Wih + (size_t)(0 * 256 + tid) * 256);
    const float4* wrow1 = (const float4*)(Wih + (size_t)(1 * 256 + tid) * 256);
    const float4* wrow2 = (const float4*)(Wih + (size_t)(2 * 256 + tid) * 256);
    const float4* wrow3 = (const float4*)(Wih + (size_t)(3 * 256 + tid) * 256);

    for (int k4 = 0; k4 < 64; ++k4) {
        float4 xv[16];
        #pragma unroll
        for (int tt = 0; tt < 16; ++tt) xv[tt] = xt[tt][k4];
        float4 w0 = wrow0[k4], w1 = wrow1[k4], w2 = wrow2[k4], w3 = wrow3[k4];
        #pragma unroll
        for (int tt = 0; tt < 16; ++tt) {
            acc[0][tt] += w0.x*xv[tt].x + w0.y*xv[tt].y + w0.z*xv[tt].z + w0.w*xv[tt].w;
            acc[1][tt] += w1.x*xv[tt].x + w1.y*xv[tt].y + w1.z*xv[tt].z + w1.w*xv[tt].w;
            acc[2][tt] += w2.x*xv[tt].x + w2.y*xv[tt].y + w2.z*xv[tt].z + w2.w*xv[tt].w;
            acc[3][tt] += w3.x*xv[tt].x + w3.y*xv[tt].y + w3.z*xv[tt].z + w3.w*xv[tt].w;
        }
    }

    #pragma unroll
    for (int ri = 0; ri < 4; ++ri) {
        int r = ri * 256 + tid;
        float b = bih[r] + bhh[r];
        #pragma unroll
        for (int tt = 0; tt < 16; ++tt)
            gates[(size_t)(t0 + tt) * 1024 + r] = acc[ri][tt] + b;
    }
}

// ---------------------------------------------------------------------------
// Kernel 2: BiLSTM recurrence. 64 blocks launched; only blockIdx%8 in {0,1}
// work (XCD-colocation heuristic: blockIdx%8 -> XCD round-robin, so the 4
// blocks of each direction share one XCD and agent-scope atomics can resolve
// at the local-L2 coherence point). 1024 threads: k split 4 ways (64 weight
// floats/thread, register-resident). Own-block h values bypass the global
// msg round trip via double-buffered LDS.
// ---------------------------------------------------------------------------
__global__ __launch_bounds__(1024, 4) void lstm_kernel(
    const float* __restrict__ Whh_f, const float* __restrict__ Whh_b,
    const float* __restrict__ gates_f, const float* __restrict__ gates_b,
    const float* __restrict__ h0, const float* __restrict__ c0,
    float* __restrict__ h_out, u64* __restrict__ msg)
{
    const int xcd  = blockIdx.x & 7;
    const int slot = blockIdx.x >> 3;
    if (xcd > 1 || slot > 3) return;   // 56 filler blocks exit immediately
    const int dir = xcd;
    const int g   = slot;

    const int tid  = threadIdx.x;
    const int quar = tid >> 8;        // k-quarter 0..3
    const int rl   = tid & 255;       // row-local 0..255
    const int gate = rl >> 6;         // 0..3 (i,f,g,o)
    const int jj   = rl & 63;
    const int j    = g * 64 + jj;     // hidden index within direction
    const int r    = gate * 256 + j;  // gate row 0..1023

    const float* Whh   = dir ? Whh_b : Whh_f;
    const float* gates = dir ? gates_b : gates_f;

    // register-resident weight quarter-row (64 floats = 16 float4)
    float4 wv[16];
    {
        const float4* wp = (const float4*)(Whh + (size_t)r * 256 + quar * 64);
        #pragma unroll
        for (int i = 0; i < 16; ++i) wv[i] = wp[i];
    }

    __shared__ __align__(16) float h_lds[2][256];
    __shared__ float part[1024];

    float c = 0.f;
    if (tid < 64) {
        c = c0[dir * HH + j];
        float h = h0[dir * HH + j];
        h_lds[0][j] = h;   // local shortcut
        u64 p = ((u64)1u << 32) | (u64)__float_as_uint(h);
        __hip_atomic_store(&msg[(0 * 2 + dir) * 256 + j], p,
                           __ATOMIC_RELAXED, __HIP_MEMORY_SCOPE_AGENT);
    }

    for (int t = 0; t < T_LEN; ++t) {
        const int tf = dir ? (T_LEN - 1 - t) : t;

        // finalists prefetch their 4 gate inputs (overlaps remote poll).
        // NOTE: row index is j (= g*64 + jj), NOT jj — R2's bug.
        float gin0 = 0.f, gin1 = 0.f, gin2 = 0.f, gin3 = 0.f;
        if (tid < 64) {
            const float* gp = gates + (size_t)tf * 1024 + j;
            gin0 = gp[0]; gin1 = gp[256]; gin2 = gp[512]; gin3 = gp[768];
        }

        // poll the 192 REMOTE h values (own 64 were written locally)
        if (tid < 256 && (tid >> 6) != g) {
            u64* slotp = &msg[((t & 1) * 2 + dir) * 256 + tid];
            const unsigned want = (unsigned)(t + 1);
            u64 m;
            do {
                m = __hip_atomic_load(slotp, __ATOMIC_RELAXED, __HIP_MEMORY_SCOPE_AGENT);
            } while ((unsigned)(m >> 32) != want);
            h_lds[t & 1][tid] = __uint_as_float((unsigned)m);
        }
        __syncthreads();

        // quarter-row dot product (64 MACs/thread)
        float p = 0.f;
        const float4* hp = (const float4*)(&h_lds[t & 1][quar * 64]);
        #pragma unroll
        for (int i = 0; i < 16; ++i) {
            float4 h4 = hp[i];
            p += wv[i].x*h4.x + wv[i].y*h4.y + wv[i].z*h4.z + wv[i].w*h4.w;
        }
        part[tid] = p;
        __syncthreads();

        if (tid < 64) {
            float ga0 = gin0 + part[jj]       + part[256 + jj] + part[512 + jj] + part[768 + jj];
            float ga1 = gin1 + part[64 + jj]  + part[320 + jj] + part[576 + jj] + part[832 + jj];
            float ga2 = gin2 + part[128 + jj] + part[384 + jj] + part[640 + jj] + part[896 + jj];
            float ga3 = gin3 + part[192 + jj] + part[448 + jj] + part[704 + jj] + part[960 + jj];
            float iv = sigmoidf_(ga0);
            float fv = sigmoidf_(ga1);
            float gv = tanhf(ga2);
            float ov = sigmoidf_(ga3);
            c = fv * c + iv * gv;
            float h = ov * tanhf(c);
            // post msg FIRST (critical path), then local LDS, then h_out
            u64 pck = ((u64)(unsigned)(t + 2) << 32) | (u64)__float_as_uint(h);
            __hip_atomic_store(&msg[(((t + 1) & 1) * 2 + dir) * 256 + j], pck,
                               __ATOMIC_RELAXED, __HIP_MEMORY_SCOPE_AGENT);
            h_lds[(t + 1) & 1][j] = h;
            h_out[(size_t)tf * 512 + dir * HH + j] = h;
        }
        // part[] reads above happen before next iter's part writes (barrier
        // after poll sits between); h_lds double-buffered by parity.
    }
}

// ---------------------------------------------------------------------------
// Kernel 3: feats[t][k] = dot(h_out[t,:], W_out[k,:]) + b_out[k]
// ---------------------------------------------------------------------------
__global__ __launch_bounds__(64) void feats_kernel(
    const float* __restrict__ h_out, const float* __restrict__ W_out,
    const float* __restrict__ b_out, float* __restrict__ feats)
{
    const int t = blockIdx.x;
    const int lane = threadIdx.x;
    const int k = lane >> 1, half = lane & 1;
    const float4* hv = (const float4*)(h_out + (size_t)t * 512 + half * 256);
    const float4* wv = (const float4*)(W_out + (size_t)k * 512 + half * 256);
    float p = 0.f;
    #pragma unroll 16
    for (int i = 0; i < 64; ++i) {
        float4 a = hv[i], b = wv[i];
        p += a.x*b.x + a.y*b.y + a.z*b.z + a.w*b.w;
    }
    p += __shfl_xor(p, 1);
    if (half == 0) feats[t * 32 + k] = p + b_out[k];
}

// ---------------------------------------------------------------------------
// Kernel 4: Viterbi. Single wave: lane = 2*j + i_half. Backpointers in
// dynamic LDS. Tree-max (depth 4) preserves first-max tie semantics:
// strict > with left-preference == lowest index wins on ties.
// ---------------------------------------------------------------------------
__global__ __launch_bounds__(64) void viterbi_kernel(
    const float* __restrict__ feats, const float* __restrict__ trans,
    float* __restrict__ out)
{
    extern __shared__ unsigned char ixs[];   // (T-1) * 32 backpointers
    __shared__ float fin[32];

    const int lane = threadIdx.x;
    const int j = lane >> 1, ih = lane & 1;

    float ttr[16];
    #pragma unroll
    for (int q = 0; q < 16; ++q) ttr[q] = trans[(ih * 16 + q) * 32 + j];

    float alpha = feats[j];

    for (int t = 1; t < T_LEN; ++t) {
        float obs = feats[t * 32 + j];
        float v[16]; int ix[16];
        #pragma unroll
        for (int q = 0; q < 16; ++q) {
            int i = ih * 16 + q;
            v[q] = (__shfl(alpha, 2 * i) + ttr[q]) + obs;
            ix[q] = i;
        }
        #pragma unroll
        for (int s = 8; s >= 1; s >>= 1)
            #pragma unroll
            for (int q = 0; q < 8; ++q)
                if (q < s && v[q + s] > v[q]) { v[q] = v[q + s]; ix[q] = ix[q + s]; }
        float best = v[0]; int barg = ix[0];

        // merge the two i-halves; prefer lower i on exact ties
        float ob = __shfl_xor(best, 1); int oa = __shfl_xor(barg, 1);
        float m0 = ih ? ob : best; int a0 = ih ? oa : barg;
        float m1 = ih ? best : ob; int a1 = ih ? barg : oa;
        float m = m0; int a = a0;
        if (m1 > m0) { m = m1; a = a1; }
        if (ih == 0) ixs[(t - 1) * 32 + j] = (unsigned char)a;
        alpha = m;
    }

    if (ih == 0) fin[j] = alpha;
    __syncthreads();

    if (lane == 0) {
        float sc = fin[0]; int cur = 0;
        for (int q = 1; q < 32; ++q)
            if (fin[q] > sc) { sc = fin[q]; cur = q; }
        out[T_LEN] = sc;
        out[T_LEN - 1] = (float)cur;
        for (int t = T_LEN - 2; t >= 0; --t) {
            cur = ixs[t * 32 + cur];
            out[t] = (float)cur;
        }
    }
}

// ---------------------------------------------------------------------------
extern "C" void kernel_launch(void* const* d_in, const int* in_sizes, int n_in,
                              void* d_out, int out_size, void* d_ws, size_t ws_size,
                              hipStream_t stream) {
    const int*   sent  = (const int*)d_in[0];
    const float* embed = (const float*)d_in[1];
    const float* Wih_f = (const float*)d_in[2];
    const float* Whh_f = (const float*)d_in[3];
    const float* bih_f = (const float*)d_in[4];
    const float* bhh_f = (const float*)d_in[5];
    const float* Wih_b = (const float*)d_in[6];
    const float* Whh_b = (const float*)d_in[7];
    const float* bih_b = (const float*)d_in[8];
    const float* bhh_b = (const float*)d_in[9];
    const float* h0    = (const float*)d_in[10];
    const float* c0    = (const float*)d_in[11];
    const float* W_out = (const float*)d_in[12];
    const float* b_out = (const float*)d_in[13];
    const float* trans = (const float*)d_in[14];
    float* out = (float*)d_out;

    float* gates_f = (float*)d_ws;                              // T*1024
    float* gates_b = gates_f + (size_t)T_LEN * 1024;            // T*1024
    float* h_out   = gates_b + (size_t)T_LEN * 1024;            // T*512
    float* feats   = h_out   + (size_t)T_LEN * 512;             // T*32
    u64*   msg     = (u64*)(feats + (size_t)T_LEN * 32);        // 2*2*256

    dim3 gproj(T_LEN / 16, 2);
    proj_kernel<<<gproj, 256, 0, stream>>>(sent, embed,
        Wih_f, bih_f, bhh_f, Wih_b, bih_b, bhh_b, gates_f, gates_b);

    lstm_kernel<<<64, 1024, 0, stream>>>(Whh_f, Whh_b, gates_f, gates_b,
                                         h0, c0, h_out, msg);

    feats_kernel<<<T_LEN, 64, 0, stream>>>(h_out, W_out, b_out, feats);

    hipFuncSetAttribute((const void*)viterbi_kernel,
                        hipFuncAttributeMaxDynamicSharedMemorySize, 132 * 1024);
    viterbi_kernel<<<1, 64, (T_LEN - 1) * 32, stream>>>(feats, trans, out);
}

// Round 4
// 7402.958 us; speedup vs baseline: 1.4089x; 1.3326x over previous
//
#include <hip/hip_runtime.h>
#include <stdint.h>

#define T_LEN 4096
#define E_DIM 256
#define HH 256

typedef unsigned long long u64;

__device__ __forceinline__ float sigmoidf_(float x) { return 1.0f / (1.0f + __expf(-x)); }
// tanh via exp identity; exact saturation at +-1 (e->inf => 1, e->0 => -1)
__device__ __forceinline__ float tanh_fast(float x) {
    float e = __expf(2.0f * x);
    return 1.0f - 2.0f / (e + 1.0f);
}

// ---------------------------------------------------------------------------
// Kernel 1: embedding gather fused with input projection.
// gates_d[t][r] = dot(Wih_d[r,:], embed[sent[t],:]) + bih_d[r] + bhh_d[r]
// ---------------------------------------------------------------------------
__global__ __launch_bounds__(256) void proj_kernel(
    const int* __restrict__ sent, const float* __restrict__ embed,
    const float* __restrict__ Wih_f, const float* __restrict__ bih_f, const float* __restrict__ bhh_f,
    const float* __restrict__ Wih_b, const float* __restrict__ bih_b, const float* __restrict__ bhh_b,
    float* __restrict__ gates_f, float* __restrict__ gates_b)
{
    __shared__ float4 xt[16][64];   // 16 timesteps x 256 floats
    const int tid = threadIdx.x;
    const int dir = blockIdx.y;
    const int t0  = blockIdx.x * 16;

    const float* Wih = dir ? Wih_b : Wih_f;
    const float* bih = dir ? bih_b : bih_f;
    const float* bhh = dir ? bhh_b : bhh_f;
    float* gates     = dir ? gates_b : gates_f;

    {   // gather 16 embedding rows into LDS (coalesced 16B/lane)
        int row = tid >> 4;
        int c   = tid & 15;
        const float4* src = (const float4*)(embed + (size_t)sent[t0 + row] * E_DIM);
        xt[row][c]      = src[c];
        xt[row][c + 16] = src[c + 16];
        xt[row][c + 32] = src[c + 32];
        xt[row][c + 48] = src[c + 48];
    }
    __syncthreads();

    float acc[4][16];
    #pragma unroll
    for (int ri = 0; ri < 4; ++ri)
        #pragma unroll
        for (int tt = 0; tt < 16; ++tt) acc[ri][tt] = 0.f;

    const float4* wrow0 = (const float4*)(Wih + (size_t)(0 * 256 + tid) * 256);
    const float4* wrow1 = (const float4*)(Wih + (size_t)(1 * 256 + tid) * 256);
    const float4* wrow2 = (const float4*)(Wih + (size_t)(2 * 256 + tid) * 256);
    const float4* wrow3 = (const float4*)(Wih + (size_t)(3 * 256 + tid) * 256);

    for (int k4 = 0; k4 < 64; ++k4) {
        float4 xv[16];
        #pragma unroll
        for (int tt = 0; tt < 16; ++tt) xv[tt] = xt[tt][k4];
        float4 w0 = wrow0[k4], w1 = wrow1[k4], w2 = wrow2[k4], w3 = wrow3[k4];
        #pragma unroll
        for (int tt = 0; tt < 16; ++tt) {
            acc[0][tt] += w0.x*xv[tt].x + w0.y*xv[tt].y + w0.z*xv[tt].z + w0.w*xv[tt].w;
            acc[1][tt] += w1.x*xv[tt].x + w1.y*xv[tt].y + w1.z*xv[tt].z + w1.w*xv[tt].w;
            acc[2][tt] += w2.x*xv[tt].x + w2.y*xv[tt].y + w2.z*xv[tt].z + w2.w*xv[tt].w;
            acc[3][tt] += w3.x*xv[tt].x + w3.y*xv[tt].y + w3.z*xv[tt].z + w3.w*xv[tt].w;
        }
    }

    #pragma unroll
    for (int ri = 0; ri < 4; ++ri) {
        int r = ri * 256 + tid;
        float b = bih[r] + bhh[r];
        #pragma unroll
        for (int tt = 0; tt < 16; ++tt)
            gates[(size_t)(t0 + tt) * 1024 + r] = acc[ri][tt] + b;
    }
}

// ---------------------------------------------------------------------------
// Kernel 2: BiLSTM recurrence. 64 blocks; only blockIdx%8 in {0,1} work
// (XCD colocation). 512 threads, __launch_bounds__(512,1): VGPR cap 512 so
// the 128 weight floats/thread stay REGISTER-RESIDENT (R3's (1024,4) cap of
// 128 made the compiler re-load 64KB/step from L2 — VGPR_Count was 52).
// Thread (j,s): all 4 gates of hidden j over k-slice s*32..s*32+31.
// k-reduce = 3-stage shfl_xor butterfly (s = low 3 lane bits) -> ONE barrier
// per step. LDS h reads rotated by (i+s)&7 -> conflict-free banks.
// ---------------------------------------------------------------------------
__global__ __launch_bounds__(512, 1) void lstm_kernel(
    const float* __restrict__ Whh_f, const float* __restrict__ Whh_b,
    const float* __restrict__ gates_f, const float* __restrict__ gates_b,
    const float* __restrict__ h0, const float* __restrict__ c0,
    float* __restrict__ h_out, u64* __restrict__ msg)
{
    const int xcd  = blockIdx.x & 7;
    const int slot = blockIdx.x >> 3;
    if (xcd > 1 || slot > 3) return;   // filler blocks exit
    const int dir = xcd;
    const int g   = slot;

    const int tid = threadIdx.x;
    const int jl  = tid >> 3;          // local hidden 0..63
    const int s   = tid & 7;           // k-slice 0..7
    const int j   = g * 64 + jl;       // global hidden index

    const float* Whh   = dir ? Whh_b : Whh_f;
    const float* gates = dir ? gates_b : gates_f;

    // wv[gg*8+i] holds Whh[gg*256+j][s*32 + ((i+s)&7)*4 .. +4]
    // (rotated so the LDS h read at issue i hits disjoint banks across s)
    float4 wv[32];
    #pragma unroll
    for (int gg = 0; gg < 4; ++gg) {
        const float4* row = (const float4*)(Whh + (size_t)(gg * 256 + j) * 256 + s * 32);
        #pragma unroll
        for (int i = 0; i < 8; ++i) {
            int idx = (i + s) & 7;
            wv[gg * 8 + i] = row[idx];
        }
    }

    __shared__ __align__(16) float h_lds[2][256];

    float c = 0.f;
    if (tid < 64) {
        int j0 = g * 64 + tid;
        float h = h0[dir * HH + j0];
        h_lds[0][j0] = h;
        u64 p = ((u64)1u << 32) | (u64)__float_as_uint(h);
        __hip_atomic_store(&msg[(0 * 2 + dir) * 256 + j0], p,
                           __ATOMIC_RELAXED, __HIP_MEMORY_SCOPE_AGENT);
    }
    if (s == 0) c = c0[dir * HH + j];

    for (int t = 0; t < T_LEN; ++t) {
        const int tf = dir ? (T_LEN - 1 - t) : t;

        // finalist lanes prefetch gate inputs (overlaps the poll)
        float gin0 = 0.f, gin1 = 0.f, gin2 = 0.f, gin3 = 0.f;
        if (s == 0) {
            const float* gp = gates + (size_t)tf * 1024 + j;
            gin0 = gp[0]; gin1 = gp[256]; gin2 = gp[512]; gin3 = gp[768];
        }

        // poll the 192 remote h values (own 64 written locally last step).
        // own slots = wave g exactly -> wave-uniform skip, no divergence.
        if (tid < 256 && (tid >> 6) != g) {
            u64* sp = &msg[((t & 1) * 2 + dir) * 256 + tid];
            const unsigned want = (unsigned)(t + 1);
            u64 m;
            do {
                m = __hip_atomic_load(sp, __ATOMIC_RELAXED, __HIP_MEMORY_SCOPE_AGENT);
            } while ((unsigned)(m >> 32) != want);
            h_lds[t & 1][tid] = __uint_as_float((unsigned)m);
        }
        __syncthreads();   // the ONLY barrier per step

        // 4-gate partial dot over this thread's 32-k slice
        float p0 = 0.f, p1 = 0.f, p2 = 0.f, p3 = 0.f;
        const float4* hp = (const float4*)(&h_lds[t & 1][s * 32]);
        #pragma unroll
        for (int i = 0; i < 8; ++i) {
            int idx = (i + s) & 7;
            float4 h4 = hp[idx];
            float4 a = wv[i], b = wv[8 + i], d = wv[16 + i], e = wv[24 + i];
            p0 += a.x*h4.x + a.y*h4.y + a.z*h4.z + a.w*h4.w;
            p1 += b.x*h4.x + b.y*h4.y + b.z*h4.z + b.w*h4.w;
            p2 += d.x*h4.x + d.y*h4.y + d.z*h4.z + d.w*h4.w;
            p3 += e.x*h4.x + e.y*h4.y + e.z*h4.z + e.w*h4.w;
        }

        // butterfly reduce across the 8 k-slices (lane bits 0..2)
        #pragma unroll
        for (int m = 1; m <= 4; m <<= 1) {
            p0 += __shfl_xor(p0, m);
            p1 += __shfl_xor(p1, m);
            p2 += __shfl_xor(p2, m);
            p3 += __shfl_xor(p3, m);
        }

        if (s == 0) {
            float iv = sigmoidf_(gin0 + p0);
            float fv = sigmoidf_(gin1 + p1);
            float gv = tanh_fast(gin2 + p2);
            float ov = sigmoidf_(gin3 + p3);
            c = fv * c + iv * gv;
            float h = ov * tanh_fast(c);
            // publish: msg first (critical path), then local LDS, then h_out
            u64 pck = ((u64)(unsigned)(t + 2) << 32) | (u64)__float_as_uint(h);
            __hip_atomic_store(&msg[(((t + 1) & 1) * 2 + dir) * 256 + j], pck,
                               __ATOMIC_RELAXED, __HIP_MEMORY_SCOPE_AGENT);
            h_lds[(t + 1) & 1][j] = h;
            h_out[(size_t)tf * 512 + dir * HH + j] = h;
        }
        // ordering: h_lds[(t+1)&1][own] writes vs readers -> step t+1 barrier;
        // vs step t-1 dot reads of same parity -> step t barrier. msg slot
        // reuse guarded by tag visibility (producer overwrites only after
        // seeing tags that imply all readers passed their barrier).
    }
}

// ---------------------------------------------------------------------------
// Kernel 3: feats[t][k] = dot(h_out[t,:], W_out[k,:]) + b_out[k]
// ---------------------------------------------------------------------------
__global__ __launch_bounds__(64) void feats_kernel(
    const float* __restrict__ h_out, const float* __restrict__ W_out,
    const float* __restrict__ b_out, float* __restrict__ feats)
{
    const int t = blockIdx.x;
    const int lane = threadIdx.x;
    const int k = lane >> 1, half = lane & 1;
    const float4* hv = (const float4*)(h_out + (size_t)t * 512 + half * 256);
    const float4* wv = (const float4*)(W_out + (size_t)k * 512 + half * 256);
    float p = 0.f;
    #pragma unroll 16
    for (int i = 0; i < 64; ++i) {
        float4 a = hv[i], b = wv[i];
        p += a.x*b.x + a.y*b.y + a.z*b.z + a.w*b.w;
    }
    p += __shfl_xor(p, 1);
    if (half == 0) feats[t * 32 + k] = p + b_out[k];
}

// ---------------------------------------------------------------------------
// Kernel 4: Viterbi. Single wave. feats chunk-preloaded into LDS (kills the
// ~600cy L3-latency obs load per serial iteration — the R3 hidden cost).
// Backpointers in LDS. Dyn LDS = 128K (ixs) + 16K (chunk) = 144K.
// ---------------------------------------------------------------------------
#define VT_CHUNK 128
__global__ __launch_bounds__(64) void viterbi_kernel(
    const float* __restrict__ feats, const float* __restrict__ trans,
    float* __restrict__ out)
{
    extern __shared__ unsigned char dynls[];
    unsigned char* ixs = dynls;                       // (T-1)*32 = 131040 B
    float* fchunk = (float*)(dynls + 131072);         // VT_CHUNK*32 floats
    __shared__ float fin[32];

    const int lane = threadIdx.x;
    const int j = lane >> 1, ih = lane & 1;

    float ttr[16];
    #pragma unroll
    for (int q = 0; q < 16; ++q) ttr[q] = trans[(ih * 16 + q) * 32 + j];

    float alpha = 0.f;

    for (int cs = 0; cs < T_LEN; cs += VT_CHUNK) {
        // coalesced bulk load of 128 timesteps of feats into LDS
        const float4* src = (const float4*)(feats + (size_t)cs * 32);
        float4* dst = (float4*)fchunk;
        #pragma unroll
        for (int i = 0; i < 16; ++i) dst[lane + 64 * i] = src[lane + 64 * i];
        __syncthreads();

        int tbeg = cs;
        if (cs == 0) { alpha = fchunk[j]; tbeg = 1; }

        for (int t = tbeg; t < cs + VT_CHUNK; ++t) {
            float obs = fchunk[(t - cs) * 32 + j];
            float v[16]; int ix[16];
            #pragma unroll
            for (int q = 0; q < 16; ++q) {
                int i = ih * 16 + q;
                v[q] = (__shfl(alpha, 2 * i) + ttr[q]) + obs;
                ix[q] = i;
            }
            #pragma unroll
            for (int st = 8; st >= 1; st >>= 1)
                #pragma unroll
                for (int q = 0; q < 8; ++q)
                    if (q < st && v[q + st] > v[q]) { v[q] = v[q + st]; ix[q] = ix[q + st]; }
            float best = v[0]; int barg = ix[0];

            // merge the two i-halves; lower i wins exact ties
            float ob = __shfl_xor(best, 1); int oa = __shfl_xor(barg, 1);
            float m0 = ih ? ob : best; int a0 = ih ? oa : barg;
            float m1 = ih ? best : ob; int a1 = ih ? barg : oa;
            float m = m0; int a = a0;
            if (m1 > m0) { m = m1; a = a1; }
            if (ih == 0) ixs[(t - 1) * 32 + j] = (unsigned char)a;
            alpha = m;
        }
        __syncthreads();   // before overwriting fchunk
    }

    if (ih == 0) fin[j] = alpha;
    __syncthreads();

    if (lane == 0) {
        float sc = fin[0]; int cur = 0;
        for (int q = 1; q < 32; ++q)
            if (fin[q] > sc) { sc = fin[q]; cur = q; }
        out[T_LEN] = sc;
        out[T_LEN - 1] = (float)cur;
        for (int t = T_LEN - 2; t >= 0; --t) {
            cur = ixs[t * 32 + cur];
            out[t] = (float)cur;
        }
    }
}

// ---------------------------------------------------------------------------
extern "C" void kernel_launch(void* const* d_in, const int* in_sizes, int n_in,
                              void* d_out, int out_size, void* d_ws, size_t ws_size,
                              hipStream_t stream) {
    const int*   sent  = (const int*)d_in[0];
    const float* embed = (const float*)d_in[1];
    const float* Wih_f = (const float*)d_in[2];
    const float* Whh_f = (const float*)d_in[3];
    const float* bih_f = (const float*)d_in[4];
    const float* bhh_f = (const float*)d_in[5];
    const float* Wih_b = (const float*)d_in[6];
    const float* Whh_b = (const float*)d_in[7];
    const float* bih_b = (const float*)d_in[8];
    const float* bhh_b = (const float*)d_in[9];
    const float* h0    = (const float*)d_in[10];
    const float* c0    = (const float*)d_in[11];
    const float* W_out = (const float*)d_in[12];
    const float* b_out = (const float*)d_in[13];
    const float* trans = (const float*)d_in[14];
    float* out = (float*)d_out;

    float* gates_f = (float*)d_ws;                              // T*1024
    float* gates_b = gates_f + (size_t)T_LEN * 1024;            // T*1024
    float* h_out   = gates_b + (size_t)T_LEN * 1024;            // T*512
    float* feats   = h_out   + (size_t)T_LEN * 512;             // T*32
    u64*   msg     = (u64*)(feats + (size_t)T_LEN * 32);        // 2*2*256

    dim3 gproj(T_LEN / 16, 2);
    proj_kernel<<<gproj, 256, 0, stream>>>(sent, embed,
        Wih_f, bih_f, bhh_f, Wih_b, bih_b, bhh_b, gates_f, gates_b);

    lstm_kernel<<<64, 512, 0, stream>>>(Whh_f, Whh_b, gates_f, gates_b,
                                        h0, c0, h_out, msg);

    feats_kernel<<<T_LEN, 64, 0, stream>>>(h_out, W_out, b_out, feats);

    hipFuncSetAttribute((const void*)viterbi_kernel,
                        hipFuncAttributeMaxDynamicSharedMemorySize, 147456);
    viterbi_kernel<<<1, 64, 147456, stream>>>(feats, trans, out);
}

// Round 5
// 7210.935 us; speedup vs baseline: 1.4464x; 1.0266x over previous
//
#include <hip/hip_runtime.h>
#include <stdint.h>

#define T_LEN 4096
#define E_DIM 256
#define HH 256

typedef unsigned long long u64;

__device__ __forceinline__ float sigmoidf_(float x) {
    // 1/(1+e^-x) with approx rcp (rel err ~1e-7, fine vs 2% score threshold)
    return __builtin_amdgcn_rcpf(1.0f + __expf(-x));
}
// tanh via exp identity; exact saturation at +-1
__device__ __forceinline__ float tanh_fast(float x) {
    float e = __expf(2.0f * x);
    return 1.0f - 2.0f * __builtin_amdgcn_rcpf(e + 1.0f);
}

// ---------------------------------------------------------------------------
// Kernel 1: embedding gather fused with input projection.
// gates_d[t][r] = dot(Wih_d[r,:], embed[sent[t],:]) + bih_d[r] + bhh_d[r]
// ---------------------------------------------------------------------------
__global__ __launch_bounds__(256) void proj_kernel(
    const int* __restrict__ sent, const float* __restrict__ embed,
    const float* __restrict__ Wih_f, const float* __restrict__ bih_f, const float* __restrict__ bhh_f,
    const float* __restrict__ Wih_b, const float* __restrict__ bih_b, const float* __restrict__ bhh_b,
    float* __restrict__ gates_f, float* __restrict__ gates_b)
{
    __shared__ float4 xt[16][64];   // 16 timesteps x 256 floats
    const int tid = threadIdx.x;
    const int dir = blockIdx.y;
    const int t0  = blockIdx.x * 16;

    const float* Wih = dir ? Wih_b : Wih_f;
    const float* bih = dir ? bih_b : bih_f;
    const float* bhh = dir ? bhh_b : bhh_f;
    float* gates     = dir ? gates_b : gates_f;

    {   // gather 16 embedding rows into LDS (coalesced 16B/lane)
        int row = tid >> 4;
        int c   = tid & 15;
        const float4* src = (const float4*)(embed + (size_t)sent[t0 + row] * E_DIM);
        xt[row][c]      = src[c];
        xt[row][c + 16] = src[c + 16];
        xt[row][c + 32] = src[c + 32];
        xt[row][c + 48] = src[c + 48];
    }
    __syncthreads();

    float acc[4][16];
    #pragma unroll
    for (int ri = 0; ri < 4; ++ri)
        #pragma unroll
        for (int tt = 0; tt < 16; ++tt) acc[ri][tt] = 0.f;

    const float4* wrow0 = (const float4*)(Wih + (size_t)(0 * 256 + tid) * 256);
    const float4* wrow1 = (const float4*)(Wih + (size_t)(1 * 256 + tid) * 256);
    const float4* wrow2 = (const float4*)(Wih + (size_t)(2 * 256 + tid) * 256);
    const float4* wrow3 = (const float4*)(Wih + (size_t)(3 * 256 + tid) * 256);

    for (int k4 = 0; k4 < 64; ++k4) {
        float4 xv[16];
        #pragma unroll
        for (int tt = 0; tt < 16; ++tt) xv[tt] = xt[tt][k4];
        float4 w0 = wrow0[k4], w1 = wrow1[k4], w2 = wrow2[k4], w3 = wrow3[k4];
        #pragma unroll
        for (int tt = 0; tt < 16; ++tt) {
            acc[0][tt] += w0.x*xv[tt].x + w0.y*xv[tt].y + w0.z*xv[tt].z + w0.w*xv[tt].w;
            acc[1][tt] += w1.x*xv[tt].x + w1.y*xv[tt].y + w1.z*xv[tt].z + w1.w*xv[tt].w;
            acc[2][tt] += w2.x*xv[tt].x + w2.y*xv[tt].y + w2.z*xv[tt].z + w2.w*xv[tt].w;
            acc[3][tt] += w3.x*xv[tt].x + w3.y*xv[tt].y + w3.z*xv[tt].z + w3.w*xv[tt].w;
        }
    }

    #pragma unroll
    for (int ri = 0; ri < 4; ++ri) {
        int r = ri * 256 + tid;
        float b = bih[r] + bhh[r];
        #pragma unroll
        for (int tt = 0; tt < 16; ++tt)
            gates[(size_t)(t0 + tt) * 1024 + r] = acc[ri][tt] + b;
    }
}

// ---------------------------------------------------------------------------
// Kernel 2: BiLSTM recurrence. 64 blocks; only blockIdx%8 in {0,1} work
// (XCD colocation). 512 threads, __launch_bounds__(512,1).
// Thread (j,s): all 4 gates of hidden j over k-slice s*32..s*32+31.
// R4 lesson (VGPR_Count=84): the compiler rematerializes the weight loads
// inside the t-loop even with a 512-VGPR cap. Fix: pin every weight float
// with an opaque asm "+v" — asm results are NOT rematerializable, forcing
// true register residency (~170 VGPR expected; marker for this round).
// ---------------------------------------------------------------------------
__global__ __launch_bounds__(512, 1) void lstm_kernel(
    const float* __restrict__ Whh_f, const float* __restrict__ Whh_b,
    const float* __restrict__ gates_f, const float* __restrict__ gates_b,
    const float* __restrict__ h0, const float* __restrict__ c0,
    float* __restrict__ h_out, u64* __restrict__ msg)
{
    const int xcd  = blockIdx.x & 7;
    const int slot = blockIdx.x >> 3;
    if (xcd > 1 || slot > 3) return;   // filler blocks exit
    const int dir = xcd;
    const int g   = slot;

    const int tid = threadIdx.x;
    const int jl  = tid >> 3;          // local hidden 0..63
    const int s   = tid & 7;           // k-slice 0..7
    const int j   = g * 64 + jl;       // global hidden index

    const float* Whh   = dir ? Whh_b : Whh_f;
    const float* gates = dir ? gates_b : gates_f;

    // w[gg*32 + i*4 + c] = Whh[gg*256+j][s*32 + ((i+s)&7)*4 + c]
    // (rotation (i+s)&7 makes the LDS h read at issue i conflict-free across s)
    float w[128];
    #pragma unroll
    for (int gg = 0; gg < 4; ++gg) {
        const float4* row = (const float4*)(Whh + (size_t)(gg * 256 + j) * 256 + s * 32);
        #pragma unroll
        for (int i = 0; i < 8; ++i) {
            float4 v = row[(i + s) & 7];
            w[gg * 32 + i * 4 + 0] = v.x;
            w[gg * 32 + i * 4 + 1] = v.y;
            w[gg * 32 + i * 4 + 2] = v.z;
            w[gg * 32 + i * 4 + 3] = v.w;
        }
    }
    // Opaque pin: values become asm outputs -> compiler cannot re-load them
    // from memory inside the loop; they must stay live in VGPRs.
    #pragma unroll
    for (int k = 0; k < 128; ++k)
        asm volatile("" : "+v"(w[k]));

    __shared__ __align__(16) float h_lds[2][256];

    float c = 0.f;
    if (tid < 64) {
        int j0 = g * 64 + tid;
        float h = h0[dir * HH + j0];
        h_lds[0][j0] = h;
        u64 p = ((u64)1u << 32) | (u64)__float_as_uint(h);
        __hip_atomic_store(&msg[(0 * 2 + dir) * 256 + j0], p,
                           __ATOMIC_RELAXED, __HIP_MEMORY_SCOPE_AGENT);
    }
    if (s == 0) c = c0[dir * HH + j];

    for (int t = 0; t < T_LEN; ++t) {
        const int tf = dir ? (T_LEN - 1 - t) : t;

        // finalist lanes prefetch gate inputs (overlaps the poll)
        float gin0 = 0.f, gin1 = 0.f, gin2 = 0.f, gin3 = 0.f;
        if (s == 0) {
            const float* gp = gates + (size_t)tf * 1024 + j;
            gin0 = gp[0]; gin1 = gp[256]; gin2 = gp[512]; gin3 = gp[768];
        }

        // poll the 192 remote h values (own 64 written locally last step).
        // own slots = wave g exactly -> wave-uniform skip, no divergence.
        if (tid < 256 && (tid >> 6) != g) {
            u64* sp = &msg[((t & 1) * 2 + dir) * 256 + tid];
            const unsigned want = (unsigned)(t + 1);
            u64 m;
            do {
                m = __hip_atomic_load(sp, __ATOMIC_RELAXED, __HIP_MEMORY_SCOPE_AGENT);
            } while ((unsigned)(m >> 32) != want);
            h_lds[t & 1][tid] = __uint_as_float((unsigned)m);
        }
        __syncthreads();   // the ONLY barrier per step

        // 4-gate partial dot over this thread's 32-k slice
        float p0 = 0.f, p1 = 0.f, p2 = 0.f, p3 = 0.f;
        const float4* hp = (const float4*)(&h_lds[t & 1][s * 32]);
        #pragma unroll
        for (int i = 0; i < 8; ++i) {
            float4 h4 = hp[(i + s) & 7];
            p0 += w[i*4+0]*h4.x + w[i*4+1]*h4.y + w[i*4+2]*h4.z + w[i*4+3]*h4.w;
            p1 += w[32+i*4+0]*h4.x + w[32+i*4+1]*h4.y + w[32+i*4+2]*h4.z + w[32+i*4+3]*h4.w;
            p2 += w[64+i*4+0]*h4.x + w[64+i*4+1]*h4.y + w[64+i*4+2]*h4.z + w[64+i*4+3]*h4.w;
            p3 += w[96+i*4+0]*h4.x + w[96+i*4+1]*h4.y + w[96+i*4+2]*h4.z + w[96+i*4+3]*h4.w;
        }

        // butterfly reduce across the 8 k-slices (lane bits 0..2)
        #pragma unroll
        for (int m = 1; m <= 4; m <<= 1) {
            p0 += __shfl_xor(p0, m);
            p1 += __shfl_xor(p1, m);
            p2 += __shfl_xor(p2, m);
            p3 += __shfl_xor(p3, m);
        }

        if (s == 0) {
            float iv = sigmoidf_(gin0 + p0);
            float fv = sigmoidf_(gin1 + p1);
            float gv = tanh_fast(gin2 + p2);
            float ov = sigmoidf_(gin3 + p3);
            c = fv * c + iv * gv;
            float h = ov * tanh_fast(c);
            // publish: msg first (critical path), then local LDS, then h_out
            u64 pck = ((u64)(unsigned)(t + 2) << 32) | (u64)__float_as_uint(h);
            __hip_atomic_store(&msg[(((t + 1) & 1) * 2 + dir) * 256 + j], pck,
                               __ATOMIC_RELAXED, __HIP_MEMORY_SCOPE_AGENT);
            h_lds[(t + 1) & 1][j] = h;
            h_out[(size_t)tf * 512 + dir * HH + j] = h;
        }
        // ABA-safe: producer only overwrites a slot (tag t+2) after seeing
        // remote tags t+1, which imply every reader consumed tag t already.
    }
}

// ---------------------------------------------------------------------------
// Kernel 3: feats[t][k] = dot(h_out[t,:], W_out[k,:]) + b_out[k]
// ---------------------------------------------------------------------------
__global__ __launch_bounds__(64) void feats_kernel(
    const float* __restrict__ h_out, const float* __restrict__ W_out,
    const float* __restrict__ b_out, float* __restrict__ feats)
{
    const int t = blockIdx.x;
    const int lane = threadIdx.x;
    const int k = lane >> 1, half = lane & 1;
    const float4* hv = (const float4*)(h_out + (size_t)t * 512 + half * 256);
    const float4* wv = (const float4*)(W_out + (size_t)k * 512 + half * 256);
    float p = 0.f;
    #pragma unroll 16
    for (int i = 0; i < 64; ++i) {
        float4 a = hv[i], b = wv[i];
        p += a.x*b.x + a.y*b.y + a.z*b.z + a.w*b.w;
    }
    p += __shfl_xor(p, 1);
    if (half == 0) feats[t * 32 + k] = p + b_out[k];
}

// ---------------------------------------------------------------------------
// Kernel 4: Viterbi. Single wave; feats chunked through LDS; backpointers in
// LDS. Dyn LDS = 128K (ixs) + 16K (chunk) = 144K.
// ---------------------------------------------------------------------------
#define VT_CHUNK 128
__global__ __launch_bounds__(64) void viterbi_kernel(
    const float* __restrict__ feats, const float* __restrict__ trans,
    float* __restrict__ out)
{
    extern __shared__ unsigned char dynls[];
    unsigned char* ixs = dynls;                       // (T-1)*32 = 131040 B
    float* fchunk = (float*)(dynls + 131072);         // VT_CHUNK*32 floats
    __shared__ float fin[32];

    const int lane = threadIdx.x;
    const int j = lane >> 1, ih = lane & 1;

    float ttr[16];
    #pragma unroll
    for (int q = 0; q < 16; ++q) ttr[q] = trans[(ih * 16 + q) * 32 + j];

    float alpha = 0.f;

    for (int cs = 0; cs < T_LEN; cs += VT_CHUNK) {
        const float4* src = (const float4*)(feats + (size_t)cs * 32);
        float4* dst = (float4*)fchunk;
        #pragma unroll
        for (int i = 0; i < 16; ++i) dst[lane + 64 * i] = src[lane + 64 * i];
        __syncthreads();

        int tbeg = cs;
        if (cs == 0) { alpha = fchunk[j]; tbeg = 1; }

        for (int t = tbeg; t < cs + VT_CHUNK; ++t) {
            float obs = fchunk[(t - cs) * 32 + j];
            float v[16]; int ix[16];
            #pragma unroll
            for (int q = 0; q < 16; ++q) {
                int i = ih * 16 + q;
                v[q] = (__shfl(alpha, 2 * i) + ttr[q]) + obs;
                ix[q] = i;
            }
            #pragma unroll
            for (int st = 8; st >= 1; st >>= 1)
                #pragma unroll
                for (int q = 0; q < 8; ++q)
                    if (q < st && v[q + st] > v[q]) { v[q] = v[q + st]; ix[q] = ix[q + st]; }
            float best = v[0]; int barg = ix[0];

            float ob = __shfl_xor(best, 1); int oa = __shfl_xor(barg, 1);
            float m0 = ih ? ob : best; int a0 = ih ? oa : barg;
            float m1 = ih ? best : ob; int a1 = ih ? barg : oa;
            float m = m0; int a = a0;
            if (m1 > m0) { m = m1; a = a1; }
            if (ih == 0) ixs[(t - 1) * 32 + j] = (unsigned char)a;
            alpha = m;
        }
        __syncthreads();
    }

    if (ih == 0) fin[j] = alpha;
    __syncthreads();

    if (lane == 0) {
        float sc = fin[0]; int cur = 0;
        for (int q = 1; q < 32; ++q)
            if (fin[q] > sc) { sc = fin[q]; cur = q; }
        out[T_LEN] = sc;
        out[T_LEN - 1] = (float)cur;
        for (int t = T_LEN - 2; t >= 0; --t) {
            cur = ixs[t * 32 + cur];
            out[t] = (float)cur;
        }
    }
}

// ---------------------------------------------------------------------------
extern "C" void kernel_launch(void* const* d_in, const int* in_sizes, int n_in,
                              void* d_out, int out_size, void* d_ws, size_t ws_size,
                              hipStream_t stream) {
    const int*   sent  = (const int*)d_in[0];
    const float* embed = (const float*)d_in[1];
    const float* Wih_f = (const float*)d_in[2];
    const float* Whh_f = (const float*)d_in[3];
    const float* bih_f = (const float*)d_in[4];
    const float* bhh_f = (const float*)d_in[5];
    const float* Wih_b = (const float*)d_in[6];
    const float* Whh_b = (const float*)d_in[7];
    const float* bih_b = (const float*)d_in[8];
    const float* bhh_b = (const float*)d_in[9];
    const float* h0    = (const float*)d_in[10];
    const float* c0    = (const float*)d_in[11];
    const float* W_out = (const float*)d_in[12];
    const float* b_out = (const float*)d_in[13];
    const float* trans = (const float*)d_in[14];
    float* out = (float*)d_out;

    float* gates_f = (float*)d_ws;                              // T*1024
    float* gates_b = gates_f + (size_t)T_LEN * 1024;            // T*1024
    float* h_out   = gates_b + (size_t)T_LEN * 1024;            // T*512
    float* feats   = h_out   + (size_t)T_LEN * 512;             // T*32
    u64*   msg     = (u64*)(feats + (size_t)T_LEN * 32);        // 2*2*256

    dim3 gproj(T_LEN / 16, 2);
    proj_kernel<<<gproj, 256, 0, stream>>>(sent, embed,
        Wih_f, bih_f, bhh_f, Wih_b, bih_b, bhh_b, gates_f, gates_b);

    lstm_kernel<<<64, 512, 0, stream>>>(Whh_f, Whh_b, gates_f, gates_b,
                                        h0, c0, h_out, msg);

    feats_kernel<<<T_LEN, 64, 0, stream>>>(h_out, W_out, b_out, feats);

    hipFuncSetAttribute((const void*)viterbi_kernel,
                        hipFuncAttributeMaxDynamicSharedMemorySize, 147456);
    viterbi_kernel<<<1, 64, 147456, stream>>>(feats, trans, out);
}